// Round 6
// baseline (649.668 us; speedup 1.0000x reference)
//
#include <hip/hip_runtime.h>
#include <math.h>

#define N_NODES 50000
#define N_EDGES 800000
#define N_GRAPHS 512
#define SLOPE 0.2f
static constexpr float EPS_BN = 1e-5f;

// ---------------- CSR build ----------------

__global__ void hist_kernel(const int* __restrict__ dst, int* __restrict__ cnt) {
    int e = blockIdx.x * blockDim.x + threadIdx.x;
    if (e < N_EDGES) atomicAdd(&cnt[dst[e]], 1);
}

// per-1024-block inclusive scan; row_ptr[n+1] = local inclusive, blk[b] = block total
__global__ void scan1_kernel(const int* __restrict__ cnt, int* __restrict__ row_ptr,
                             int* __restrict__ blk) {
    __shared__ int tmp[1024];
    int t = threadIdx.x;
    int n = blockIdx.x * 1024 + t;
    int v = (n < N_NODES) ? cnt[n] : 0;
    tmp[t] = v;
    __syncthreads();
    for (int off = 1; off < 1024; off <<= 1) {
        int x = (t >= off) ? tmp[t - off] : 0;
        __syncthreads();
        tmp[t] += x;
        __syncthreads();
    }
    if (n < N_NODES) row_ptr[n + 1] = tmp[t];
    if (t == 1023) blk[blockIdx.x] = tmp[t];
}

// finalize row_ptr with cross-block prefix (49 totals, L1-hot) AND write scatter cursors.
__global__ void scan23f_kernel(int* __restrict__ row_ptr, const int* __restrict__ blk,
                               int* __restrict__ fill) {
    int n = blockIdx.x * blockDim.x + threadIdx.x;
    if (n >= N_NODES) return;
    int b = n >> 10;
    int pref = 0;
    for (int i = 0; i < b; ++i) pref += blk[i];
    int v = row_ptr[n + 1] + pref;
    row_ptr[n + 1] = v;
    fill[n + 1] = v;           // fill sized N_NODES+1; fill[n] == row_ptr[n]
    if (n == 0) { row_ptr[0] = 0; fill[0] = 0; }
}

// scatter edges into CSR position order; also permutes edge attrs
__global__ void scatter_kernel(const int* __restrict__ src, const int* __restrict__ dst,
                               const float* __restrict__ ea,
                               int* __restrict__ fill,
                               int* __restrict__ srcP, float4* __restrict__ eaP4) {
    int e = blockIdx.x * blockDim.x + threadIdx.x;
    if (e < N_EDGES) {
        int pos = atomicAdd(&fill[dst[e]], 1);
        srcP[pos] = src[e];
        eaP4[pos] = make_float4(ea[e * 3 + 0], ea[e * 3 + 1], ea[e * 3 + 2], 0.f);
    }
}

// ---------------- node transform: persistent weight columns in VGPRs ----------------

template <int K>
__global__ __launch_bounds__(256, 3) void transform2_kernel(
    const float* __restrict__ h,
    const float* __restrict__ Wl, const float* __restrict__ bl,
    const float* __restrict__ Wr, const float* __restrict__ br,
    float* __restrict__ xl, float* __restrict__ xr) {
    int t = threadIdx.x;
    int w = t >> 6;
    int k = t & 63;
    float wl[K], wr[K];
#pragma unroll
    for (int j = 0; j < K; j++) { wl[j] = Wl[j * 64 + k]; wr[j] = Wr[j * 64 + k]; }
    float blk = bl[k], brk = br[k];
    int wid = blockIdx.x * 4 + w;
    const int NW = gridDim.x * 4;
    for (int n = wid; n < N_NODES; n += NW) {
        float hv = (k < K) ? h[n * K + k] : 0.f;
        float al = blk, ar = brk;
#pragma unroll
        for (int j = 0; j < K; j++) {
            float hj = __int_as_float(__builtin_amdgcn_readlane(__float_as_int(hv), j));
            al = fmaf(hj, wl[j], al);
            ar = fmaf(hj, wr[j], ar);
        }
        xl[n * 64 + k] = al;
        xr[n * 64 + k] = ar;
    }
}

// ---------------- fused GATv2 layer: register-only, one wave/node, 8 edges in flight ----
// lane = 16*q + r: group q covers edge slots, lane holds features 4r..4r+3 (float4).
// Two independent 4-edge streams (A/B) per iteration -> two independent
// gather/butterfly/exp chains the scheduler can interleave (ILP x2).
// Softmax without max-subtraction (validated R4/R5): logits O(1), exp-safe.

__global__ __launch_bounds__(256) void gat_fused3_kernel(
    const float* __restrict__ xl, const float* __restrict__ xr,
    const float4* __restrict__ eaP4,
    const int* __restrict__ srcP, const int* __restrict__ row_ptr,
    const float* __restrict__ We, const float* __restrict__ att,
    const float* __restrict__ bo,
    const float* __restrict__ bn_g, const float* __restrict__ bn_b,
    const float* __restrict__ bn_m, const float* __restrict__ bn_v,
    float* __restrict__ hout) {
    int t = threadIdx.x;
    int w = t >> 6;
    int lane = t & 63;
    int q = lane >> 4;       // edge slot within 4-edge group
    int r = lane & 15;       // feature quad
    int k4 = r * 4;
    int n = blockIdx.x * 4 + w;   // grid exact: 12500*4

    float4 we0 = *(const float4*)(We + 0 * 64 + k4);
    float4 we1 = *(const float4*)(We + 64 + k4);
    float4 we2 = *(const float4*)(We + 128 + k4);
    float4 at  = *(const float4*)(att + k4);
    float4 xr4 = *(const float4*)(xr + (size_t)n * 64 + k4);
    int beg = row_ptr[n], end = row_ptr[n + 1];

    float4 oA = make_float4(0.f, 0.f, 0.f, 0.f);
    float4 oB = make_float4(0.f, 0.f, 0.f, 0.f);
    float zA = 0.f, zB = 0.f;

    for (int c = beg; c < end; c += 8) {
        int pA = c + q;     bool vA = pA < end; int iA = vA ? pA : beg;
        int pB = c + 4 + q; bool vB = pB < end; int iB = vB ? pB : beg;
        int sA = srcP[iA];
        int sB = srcP[iB];
        float4 evA = eaP4[iA];
        float4 evB = eaP4[iB];
        float4 xvA = *(const float4*)(xl + (size_t)sA * 64 + k4);
        float4 xvB = *(const float4*)(xl + (size_t)sB * 64 + k4);

        float a0 = xvA.x + xr4.x + evA.x * we0.x + evA.y * we1.x + evA.z * we2.x;
        float a1 = xvA.y + xr4.y + evA.x * we0.y + evA.y * we1.y + evA.z * we2.y;
        float a2 = xvA.z + xr4.z + evA.x * we0.z + evA.y * we1.z + evA.z * we2.z;
        float a3 = xvA.w + xr4.w + evA.x * we0.w + evA.y * we1.w + evA.z * we2.w;
        float b0 = xvB.x + xr4.x + evB.x * we0.x + evB.y * we1.x + evB.z * we2.x;
        float b1 = xvB.y + xr4.y + evB.x * we0.y + evB.y * we1.y + evB.z * we2.y;
        float b2 = xvB.z + xr4.z + evB.x * we0.z + evB.y * we1.z + evB.z * we2.z;
        float b3 = xvB.w + xr4.w + evB.x * we0.w + evB.y * we1.w + evB.z * we2.w;
        a0 = (a0 > 0.f) ? a0 : SLOPE * a0;  b0 = (b0 > 0.f) ? b0 : SLOPE * b0;
        a1 = (a1 > 0.f) ? a1 : SLOPE * a1;  b1 = (b1 > 0.f) ? b1 : SLOPE * b1;
        a2 = (a2 > 0.f) ? a2 : SLOPE * a2;  b2 = (b2 > 0.f) ? b2 : SLOPE * b2;
        a3 = (a3 > 0.f) ? a3 : SLOPE * a3;  b3 = (b3 > 0.f) ? b3 : SLOPE * b3;
        float accA = at.x * a0; accA = fmaf(at.y, a1, accA);
        accA = fmaf(at.z, a2, accA); accA = fmaf(at.w, a3, accA);
        float accB = at.x * b0; accB = fmaf(at.y, b1, accB);
        accB = fmaf(at.z, b2, accB); accB = fmaf(at.w, b3, accB);

        // two independent 16-lane butterflies, interleaved
        accA += __shfl_xor(accA, 1, 64);  accB += __shfl_xor(accB, 1, 64);
        accA += __shfl_xor(accA, 2, 64);  accB += __shfl_xor(accB, 2, 64);
        accA += __shfl_xor(accA, 4, 64);  accB += __shfl_xor(accB, 4, 64);
        accA += __shfl_xor(accA, 8, 64);  accB += __shfl_xor(accB, 8, 64);

        float peA = vA ? __expf(accA) : 0.f;
        float peB = vB ? __expf(accB) : 0.f;
        oA.x = fmaf(peA, xvA.x, oA.x);  oB.x = fmaf(peB, xvB.x, oB.x);
        oA.y = fmaf(peA, xvA.y, oA.y);  oB.y = fmaf(peB, xvB.y, oB.y);
        oA.z = fmaf(peA, xvA.z, oA.z);  oB.z = fmaf(peB, xvB.z, oB.z);
        oA.w = fmaf(peA, xvA.w, oA.w);  oB.w = fmaf(peB, xvB.w, oB.w);
        zA += peA; zB += peB;
    }

    float4 o = make_float4(oA.x + oB.x, oA.y + oB.y, oA.z + oB.z, oA.w + oB.w);
    float z = zA + zB;
    // combine the 4 q-groups
    o.x += __shfl_xor(o.x, 16, 64); o.x += __shfl_xor(o.x, 32, 64);
    o.y += __shfl_xor(o.y, 16, 64); o.y += __shfl_xor(o.y, 32, 64);
    o.z += __shfl_xor(o.z, 16, 64); o.z += __shfl_xor(o.z, 32, 64);
    o.w += __shfl_xor(o.w, 16, 64); o.w += __shfl_xor(o.w, 32, 64);
    z += __shfl_xor(z, 16, 64); z += __shfl_xor(z, 32, 64);

    if (q == 0) {
        float zi = 1.0f / fmaxf(z, 1e-16f);
        float4 bo4 = *(const float4*)(bo + k4);
        float4 g4  = *(const float4*)(bn_g + k4);
        float4 b4  = *(const float4*)(bn_b + k4);
        float4 m4  = *(const float4*)(bn_m + k4);
        float4 v4  = *(const float4*)(bn_v + k4);
        float4 res;
        res.x = fmaxf((o.x * zi + bo4.x - m4.x) * (g4.x / sqrtf(v4.x + EPS_BN)) + b4.x, 0.f);
        res.y = fmaxf((o.y * zi + bo4.y - m4.y) * (g4.y / sqrtf(v4.y + EPS_BN)) + b4.y, 0.f);
        res.z = fmaxf((o.z * zi + bo4.z - m4.z) * (g4.z / sqrtf(v4.z + EPS_BN)) + b4.z, 0.f);
        res.w = fmaxf((o.w * zi + bo4.w - m4.w) * (g4.w / sqrtf(v4.w + EPS_BN)) + b4.w, 0.f);
        *(float4*)(hout + (size_t)n * 64 + k4) = res;
    }
}

// ---------------- readout: all-in-one (binary search + folded Wjk@Whead + pool) ------

__global__ __launch_bounds__(64) void pool_all_kernel(
    const float* __restrict__ h, const int* __restrict__ batch,
    const float* __restrict__ Wjk, const float* __restrict__ bjk,
    const float* __restrict__ Whead, const float* __restrict__ bhead,
    float* __restrict__ out) {
    int g = blockIdx.x;
    int k = threadIdx.x;
    // lower_bound(batch, g) and lower_bound(batch, g+1)
    int lo = 0, hi = N_NODES;
    while (lo < hi) { int mid = (lo + hi) >> 1; if (batch[mid] < g) lo = mid + 1; else hi = mid; }
    int s = lo;
    hi = N_NODES;
    while (lo < hi) { int mid = (lo + hi) >> 1; if (batch[mid] < g + 1) lo = mid + 1; else hi = mid; }
    int e = lo;

    // wcomb_k = sum_j Wjk[k][j] * Whead[j]   (16 KB, L2-hot across blocks)
    float hw = Whead[k];
    float wc = 0.f;
    for (int j = 0; j < 64; j++) wc = fmaf(Wjk[k * 64 + j], Whead[j], wc);
    // bcomb = sum_j bjk[j]*Whead[j]
    float bc = bjk[k] * hw;
    for (int off = 32; off > 0; off >>= 1) bc += __shfl_xor(bc, off, 64);

    float acc = 0.f;
    for (int n = s; n < e; ++n) acc += h[(size_t)n * 64 + k];
    float cnt = (float)(e - s);
    acc /= fmaxf(cnt, 1.0f);
    float v = acc * wc;
    for (int off = 32; off > 0; off >>= 1) v += __shfl_xor(v, off, 64);
    if (k == 0) out[g] = v + bc + bhead[0];
}

// ---------------- launch ----------------

extern "C" void kernel_launch(void* const* d_in, const int* in_sizes, int n_in,
                              void* d_out, int out_size, void* d_ws, size_t ws_size,
                              hipStream_t stream) {
    const float* x     = (const float*)d_in[0];
    const float* ea    = (const float*)d_in[1];
    const float* Wl0   = (const float*)d_in[2];
    const float* Wr0   = (const float*)d_in[3];
    const float* bl0   = (const float*)d_in[4];
    const float* br0   = (const float*)d_in[5];
    const float* We0   = (const float*)d_in[6];
    const float* att0  = (const float*)d_in[7];
    const float* bo0   = (const float*)d_in[8];
    const float* Wl    = (const float*)d_in[9];
    const float* Wr    = (const float*)d_in[10];
    const float* bl    = (const float*)d_in[11];
    const float* br    = (const float*)d_in[12];
    const float* We    = (const float*)d_in[13];
    const float* att   = (const float*)d_in[14];
    const float* bo    = (const float*)d_in[15];
    const float* bn_g  = (const float*)d_in[16];
    const float* bn_b  = (const float*)d_in[17];
    const float* bn_m  = (const float*)d_in[18];
    const float* bn_v  = (const float*)d_in[19];
    const float* Wjk   = (const float*)d_in[20];
    const float* bjk   = (const float*)d_in[21];
    const float* Whead = (const float*)d_in[22];
    const float* bhead = (const float*)d_in[23];
    const int* edge_index = (const int*)d_in[24];
    const int* batch      = (const int*)d_in[25];

    const int* srcIdx = edge_index;            // edge_index[0]
    const int* dstIdx = edge_index + N_EDGES;  // edge_index[1]

    char* ws = (char*)d_ws;
    size_t off = 0;
    auto alloc = [&](size_t bytes) -> void* {
        void* p = ws + off;
        off += (bytes + 255) & ~(size_t)255;
        return p;
    };
    float* hA      = (float*)alloc((size_t)N_NODES * 64 * 4);
    float* hB      = (float*)alloc((size_t)N_NODES * 64 * 4);
    float* xlb     = (float*)alloc((size_t)N_NODES * 64 * 4);
    float* xrb     = (float*)alloc((size_t)N_NODES * 64 * 4);
    int*   row_ptr = (int*)alloc((size_t)(N_NODES + 1) * 4);
    int*   fill    = (int*)alloc((size_t)(N_NODES + 1) * 4);
    int*   blk     = (int*)alloc(64 * 4);
    int*   srcP    = (int*)alloc((size_t)N_EDGES * 4);
    float4* eaP4   = (float4*)alloc((size_t)N_EDGES * 16);

    // ---- CSR build (sort edges by dst): 5 dispatches ----
    hipMemsetAsync(fill, 0, (size_t)N_NODES * 4, stream);
    hist_kernel<<<(N_EDGES + 255) / 256, 256, 0, stream>>>(dstIdx, fill);
    const int SCB = (N_NODES + 1023) / 1024;  // 49
    scan1_kernel<<<SCB, 1024, 0, stream>>>(fill, row_ptr, blk);
    scan23f_kernel<<<(N_NODES + 255) / 256, 256, 0, stream>>>(row_ptr, blk, fill);
    scatter_kernel<<<(N_EDGES + 255) / 256, 256, 0, stream>>>(srcIdx, dstIdx, ea, fill, srcP, eaP4);

    const int NBN = N_NODES / 4;   // 12500 (fused gat grid)
    const int NBT = 512;           // transform grid (persistent)

    // ---- layer 0 (input dim 9) ----
    transform2_kernel<9><<<NBT, 256, 0, stream>>>(x, Wl0, bl0, Wr0, br0, xlb, xrb);
    gat_fused3_kernel<<<NBN, 256, 0, stream>>>(xlb, xrb, eaP4, srcP, row_ptr,
                                               We0, att0, bo0,
                                               bn_g, bn_b, bn_m, bn_v, hA);

    // ---- layers 1..4 ----
    float* hcur = hA;
    float* hnext = hB;
    for (int i = 0; i < 4; i++) {
        transform2_kernel<64><<<NBT, 256, 0, stream>>>(hcur,
            Wl + (size_t)i * 64 * 64, bl + (size_t)i * 64,
            Wr + (size_t)i * 64 * 64, br + (size_t)i * 64,
            xlb, xrb);
        gat_fused3_kernel<<<NBN, 256, 0, stream>>>(xlb, xrb, eaP4, srcP, row_ptr,
            We + (size_t)i * 3 * 64, att + (size_t)i * 64,
            bo + (size_t)i * 64,
            bn_g + (size_t)(i + 1) * 64, bn_b + (size_t)(i + 1) * 64,
            bn_m + (size_t)(i + 1) * 64, bn_v + (size_t)(i + 1) * 64,
            hnext);
        float* tp = hcur; hcur = hnext; hnext = tp;
    }

    // ---- readout: single dispatch ----
    pool_all_kernel<<<N_GRAPHS, 64, 0, stream>>>(hcur, batch, Wjk, bjk, Whead, bhead,
                                                 (float*)d_out);
}

// Round 7
// 577.976 us; speedup vs baseline: 1.1240x; 1.1240x over previous
//
#include <hip/hip_runtime.h>
#include <math.h>

#define N_NODES 50000
#define N_EDGES 800000
#define N_GRAPHS 512
#define SLOPE 0.2f
static constexpr float EPS_BN = 1e-5f;

typedef float v2f __attribute__((ext_vector_type(2)));

// ---------------- CSR build ----------------

__global__ void hist_kernel(const int* __restrict__ dst, int* __restrict__ cnt) {
    int e = blockIdx.x * blockDim.x + threadIdx.x;
    if (e < N_EDGES) atomicAdd(&cnt[dst[e]], 1);
}

// per-1024-block inclusive scan; row_ptr[n+1] = local inclusive, blk[b] = block total
__global__ void scan1_kernel(const int* __restrict__ cnt, int* __restrict__ row_ptr,
                             int* __restrict__ blk) {
    __shared__ int tmp[1024];
    int t = threadIdx.x;
    int n = blockIdx.x * 1024 + t;
    int v = (n < N_NODES) ? cnt[n] : 0;
    tmp[t] = v;
    __syncthreads();
    for (int off = 1; off < 1024; off <<= 1) {
        int x = (t >= off) ? tmp[t - off] : 0;
        __syncthreads();
        tmp[t] += x;
        __syncthreads();
    }
    if (n < N_NODES) row_ptr[n + 1] = tmp[t];
    if (t == 1023) blk[blockIdx.x] = tmp[t];
}

// finalize row_ptr with cross-block prefix (49 totals, L1-hot) AND write scatter cursors.
__global__ void scan23f_kernel(int* __restrict__ row_ptr, const int* __restrict__ blk,
                               int* __restrict__ fill) {
    int n = blockIdx.x * blockDim.x + threadIdx.x;
    if (n >= N_NODES) return;
    int b = n >> 10;
    int pref = 0;
    for (int i = 0; i < b; ++i) pref += blk[i];
    int v = row_ptr[n + 1] + pref;
    row_ptr[n + 1] = v;
    fill[n + 1] = v;
    if (n == 0) { row_ptr[0] = 0; fill[0] = 0; }
}

// scatter edges into CSR order as ONE 16B record per edge: {src_bits, e0, e1, e2}
__global__ void scatter_kernel(const int* __restrict__ src, const int* __restrict__ dst,
                               const float* __restrict__ ea,
                               int* __restrict__ fill,
                               float4* __restrict__ rec) {
    int e = blockIdx.x * blockDim.x + threadIdx.x;
    if (e < N_EDGES) {
        int pos = atomicAdd(&fill[dst[e]], 1);
        rec[pos] = make_float4(__int_as_float(src[e]),
                               ea[e * 3 + 0], ea[e * 3 + 1], ea[e * 3 + 2]);
    }
}

// ---------------- node transform: persistent weight columns in VGPRs ----------------

template <int K>
__global__ __launch_bounds__(256, 2) void transform2_kernel(
    const float* __restrict__ h,
    const float* __restrict__ Wl, const float* __restrict__ bl,
    const float* __restrict__ Wr, const float* __restrict__ br,
    float* __restrict__ xl, float* __restrict__ xr) {
    int t = threadIdx.x;
    int w = t >> 6;
    int k = t & 63;
    float wl[K], wr[K];
#pragma unroll
    for (int j = 0; j < K; j++) { wl[j] = Wl[j * 64 + k]; wr[j] = Wr[j * 64 + k]; }
    float blk = bl[k], brk = br[k];
    int wid = blockIdx.x * 4 + w;
    const int NW = gridDim.x * 4;
    for (int n = wid; n < N_NODES; n += NW) {
        float hv = (k < K) ? h[n * K + k] : 0.f;
        float al = blk, ar = brk;
#pragma unroll
        for (int j = 0; j < K; j++) {
            float hj = __int_as_float(__builtin_amdgcn_readlane(__float_as_int(hv), j));
            al = fmaf(hj, wl[j], al);
            ar = fmaf(hj, wr[j], ar);
        }
        xl[n * 64 + k] = al;
        xr[n * 64 + k] = ar;
    }
}

// ---------------- fused GATv2 layer: packed-f32, one wave/node, 8 edges in flight ----
// lane = 16*q + r: group q covers edge slots, lane holds features 4r..4r+3.
// Feature math on float2 ext-vectors -> v_pk_fma_f32 / v_pk_max_f32 (2x f32 per issue).
// leaky(t) = max(t, 0.2t) (bit-identical for slope<1). No max-subtraction softmax
// (validated R4/R5). One 16B record load per edge slot. No LDS, no barriers.

__global__ __launch_bounds__(256) void gat_fused4_kernel(
    const float* __restrict__ xl, const float* __restrict__ xr,
    const float4* __restrict__ recP, const int* __restrict__ row_ptr,
    const float* __restrict__ We, const float* __restrict__ att,
    const float* __restrict__ bo,
    const float* __restrict__ bn_g, const float* __restrict__ bn_b,
    const float* __restrict__ bn_m, const float* __restrict__ bn_v,
    float* __restrict__ hout) {
    int t = threadIdx.x;
    int w = t >> 6;
    int lane = t & 63;
    int q = lane >> 4;       // edge slot within 4-edge group
    int r = lane & 15;       // feature quad
    int k4 = r * 4;
    int n = blockIdx.x * 4 + w;   // grid exact: 12500*4

    float4 we0 = *(const float4*)(We + 0 * 64 + k4);
    float4 we1 = *(const float4*)(We + 64 + k4);
    float4 we2 = *(const float4*)(We + 128 + k4);
    float4 at4 = *(const float4*)(att + k4);
    float4 xq  = *(const float4*)(xr + (size_t)n * 64 + k4);
    v2f we0a = {we0.x, we0.y}, we0b = {we0.z, we0.w};
    v2f we1a = {we1.x, we1.y}, we1b = {we1.z, we1.w};
    v2f we2a = {we2.x, we2.y}, we2b = {we2.z, we2.w};
    v2f ata  = {at4.x, at4.y}, atb  = {at4.z, at4.w};
    v2f xra  = {xq.x, xq.y},   xrb  = {xq.z, xq.w};
    int beg = row_ptr[n], end = row_ptr[n + 1];

    v2f oAa = {0.f, 0.f}, oAb = {0.f, 0.f};
    v2f oBa = {0.f, 0.f}, oBb = {0.f, 0.f};
    float zA = 0.f, zB = 0.f;

    for (int c = beg; c < end; c += 8) {
        int pA = c + q;     bool vA = pA < end; int iA = vA ? pA : beg;
        int pB = c + 4 + q; bool vB = pB < end; int iB = vB ? pB : beg;
        float4 rA = recP[iA];
        float4 rB = recP[iB];
        int sA = __float_as_int(rA.x);
        int sB = __float_as_int(rB.x);
        float4 xA = *(const float4*)(xl + (size_t)sA * 64 + k4);
        float4 xB = *(const float4*)(xl + (size_t)sB * 64 + k4);
        v2f xAa = {xA.x, xA.y}, xAb = {xA.z, xA.w};
        v2f xBa = {xB.x, xB.y}, xBb = {xB.z, xB.w};

        v2f tAa = xAa + xra, tAb = xAb + xrb;
        v2f tBa = xBa + xra, tBb = xBb + xrb;
        tAa = __builtin_elementwise_fma((v2f){rA.y, rA.y}, we0a, tAa);
        tAb = __builtin_elementwise_fma((v2f){rA.y, rA.y}, we0b, tAb);
        tBa = __builtin_elementwise_fma((v2f){rB.y, rB.y}, we0a, tBa);
        tBb = __builtin_elementwise_fma((v2f){rB.y, rB.y}, we0b, tBb);
        tAa = __builtin_elementwise_fma((v2f){rA.z, rA.z}, we1a, tAa);
        tAb = __builtin_elementwise_fma((v2f){rA.z, rA.z}, we1b, tAb);
        tBa = __builtin_elementwise_fma((v2f){rB.z, rB.z}, we1a, tBa);
        tBb = __builtin_elementwise_fma((v2f){rB.z, rB.z}, we1b, tBb);
        tAa = __builtin_elementwise_fma((v2f){rA.w, rA.w}, we2a, tAa);
        tAb = __builtin_elementwise_fma((v2f){rA.w, rA.w}, we2b, tAb);
        tBa = __builtin_elementwise_fma((v2f){rB.w, rB.w}, we2a, tBa);
        tBb = __builtin_elementwise_fma((v2f){rB.w, rB.w}, we2b, tBb);

        // leaky = max(t, 0.2*t)
        tAa = __builtin_elementwise_max(tAa, tAa * SLOPE);
        tAb = __builtin_elementwise_max(tAb, tAb * SLOPE);
        tBa = __builtin_elementwise_max(tBa, tBa * SLOPE);
        tBb = __builtin_elementwise_max(tBb, tBb * SLOPE);

        v2f dA = ata * tAa; dA = __builtin_elementwise_fma(atb, tAb, dA);
        v2f dB = ata * tBa; dB = __builtin_elementwise_fma(atb, tBb, dB);
        float accA = dA.x + dA.y;
        float accB = dB.x + dB.y;

        accA += __shfl_xor(accA, 1, 64);  accB += __shfl_xor(accB, 1, 64);
        accA += __shfl_xor(accA, 2, 64);  accB += __shfl_xor(accB, 2, 64);
        accA += __shfl_xor(accA, 4, 64);  accB += __shfl_xor(accB, 4, 64);
        accA += __shfl_xor(accA, 8, 64);  accB += __shfl_xor(accB, 8, 64);

        float peA = vA ? __expf(accA) : 0.f;
        float peB = vB ? __expf(accB) : 0.f;
        v2f pA2 = {peA, peA}, pB2 = {peB, peB};
        oAa = __builtin_elementwise_fma(pA2, xAa, oAa);
        oAb = __builtin_elementwise_fma(pA2, xAb, oAb);
        oBa = __builtin_elementwise_fma(pB2, xBa, oBa);
        oBb = __builtin_elementwise_fma(pB2, xBb, oBb);
        zA += peA; zB += peB;
    }

    v2f oa = oAa + oBa, ob = oAb + oBb;
    float z = zA + zB;
    float4 o = make_float4(oa.x, oa.y, ob.x, ob.y);
    o.x += __shfl_xor(o.x, 16, 64); o.x += __shfl_xor(o.x, 32, 64);
    o.y += __shfl_xor(o.y, 16, 64); o.y += __shfl_xor(o.y, 32, 64);
    o.z += __shfl_xor(o.z, 16, 64); o.z += __shfl_xor(o.z, 32, 64);
    o.w += __shfl_xor(o.w, 16, 64); o.w += __shfl_xor(o.w, 32, 64);
    z += __shfl_xor(z, 16, 64); z += __shfl_xor(z, 32, 64);

    if (q == 0) {
        float zi = 1.0f / fmaxf(z, 1e-16f);
        float4 bo4 = *(const float4*)(bo + k4);
        float4 g4  = *(const float4*)(bn_g + k4);
        float4 b4  = *(const float4*)(bn_b + k4);
        float4 m4  = *(const float4*)(bn_m + k4);
        float4 v4  = *(const float4*)(bn_v + k4);
        float4 res;
        res.x = fmaxf((o.x * zi + bo4.x - m4.x) * (g4.x / sqrtf(v4.x + EPS_BN)) + b4.x, 0.f);
        res.y = fmaxf((o.y * zi + bo4.y - m4.y) * (g4.y / sqrtf(v4.y + EPS_BN)) + b4.y, 0.f);
        res.z = fmaxf((o.z * zi + bo4.z - m4.z) * (g4.z / sqrtf(v4.z + EPS_BN)) + b4.z, 0.f);
        res.w = fmaxf((o.w * zi + bo4.w - m4.w) * (g4.w / sqrtf(v4.w + EPS_BN)) + b4.w, 0.f);
        *(float4*)(hout + (size_t)n * 64 + k4) = res;
    }
}

// ---------------- readout: all-in-one ----------------

__global__ __launch_bounds__(64) void pool_all_kernel(
    const float* __restrict__ h, const int* __restrict__ batch,
    const float* __restrict__ Wjk, const float* __restrict__ bjk,
    const float* __restrict__ Whead, const float* __restrict__ bhead,
    float* __restrict__ out) {
    int g = blockIdx.x;
    int k = threadIdx.x;
    int lo = 0, hi = N_NODES;
    while (lo < hi) { int mid = (lo + hi) >> 1; if (batch[mid] < g) lo = mid + 1; else hi = mid; }
    int s = lo;
    hi = N_NODES;
    while (lo < hi) { int mid = (lo + hi) >> 1; if (batch[mid] < g + 1) lo = mid + 1; else hi = mid; }
    int e = lo;

    float wc = 0.f;
    for (int j = 0; j < 64; j++) wc = fmaf(Wjk[k * 64 + j], Whead[j], wc);
    float bc = bjk[k] * Whead[k];
    for (int off = 32; off > 0; off >>= 1) bc += __shfl_xor(bc, off, 64);

    float acc = 0.f;
    for (int n = s; n < e; ++n) acc += h[(size_t)n * 64 + k];
    float cnt = (float)(e - s);
    acc /= fmaxf(cnt, 1.0f);
    float v = acc * wc;
    for (int off = 32; off > 0; off >>= 1) v += __shfl_xor(v, off, 64);
    if (k == 0) out[g] = v + bc + bhead[0];
}

// ---------------- launch ----------------

extern "C" void kernel_launch(void* const* d_in, const int* in_sizes, int n_in,
                              void* d_out, int out_size, void* d_ws, size_t ws_size,
                              hipStream_t stream) {
    const float* x     = (const float*)d_in[0];
    const float* ea    = (const float*)d_in[1];
    const float* Wl0   = (const float*)d_in[2];
    const float* Wr0   = (const float*)d_in[3];
    const float* bl0   = (const float*)d_in[4];
    const float* br0   = (const float*)d_in[5];
    const float* We0   = (const float*)d_in[6];
    const float* att0  = (const float*)d_in[7];
    const float* bo0   = (const float*)d_in[8];
    const float* Wl    = (const float*)d_in[9];
    const float* Wr    = (const float*)d_in[10];
    const float* bl    = (const float*)d_in[11];
    const float* br    = (const float*)d_in[12];
    const float* We    = (const float*)d_in[13];
    const float* att   = (const float*)d_in[14];
    const float* bo    = (const float*)d_in[15];
    const float* bn_g  = (const float*)d_in[16];
    const float* bn_b  = (const float*)d_in[17];
    const float* bn_m  = (const float*)d_in[18];
    const float* bn_v  = (const float*)d_in[19];
    const float* Wjk   = (const float*)d_in[20];
    const float* bjk   = (const float*)d_in[21];
    const float* Whead = (const float*)d_in[22];
    const float* bhead = (const float*)d_in[23];
    const int* edge_index = (const int*)d_in[24];
    const int* batch      = (const int*)d_in[25];

    const int* srcIdx = edge_index;            // edge_index[0]
    const int* dstIdx = edge_index + N_EDGES;  // edge_index[1]

    char* ws = (char*)d_ws;
    size_t off = 0;
    auto alloc = [&](size_t bytes) -> void* {
        void* p = ws + off;
        off += (bytes + 255) & ~(size_t)255;
        return p;
    };
    float* hA      = (float*)alloc((size_t)N_NODES * 64 * 4);
    float* hB      = (float*)alloc((size_t)N_NODES * 64 * 4);
    float* xlb     = (float*)alloc((size_t)N_NODES * 64 * 4);
    float* xrb     = (float*)alloc((size_t)N_NODES * 64 * 4);
    int*   row_ptr = (int*)alloc((size_t)(N_NODES + 1) * 4);
    int*   fill    = (int*)alloc((size_t)(N_NODES + 1) * 4);
    int*   blk     = (int*)alloc(64 * 4);
    float4* recP   = (float4*)alloc((size_t)N_EDGES * 16);

    // ---- CSR build (sort edges by dst) ----
    hipMemsetAsync(fill, 0, (size_t)N_NODES * 4, stream);
    hist_kernel<<<(N_EDGES + 255) / 256, 256, 0, stream>>>(dstIdx, fill);
    const int SCB = (N_NODES + 1023) / 1024;  // 49
    scan1_kernel<<<SCB, 1024, 0, stream>>>(fill, row_ptr, blk);
    scan23f_kernel<<<(N_NODES + 255) / 256, 256, 0, stream>>>(row_ptr, blk, fill);
    scatter_kernel<<<(N_EDGES + 255) / 256, 256, 0, stream>>>(srcIdx, dstIdx, ea, fill, recP);

    const int NBN = N_NODES / 4;   // 12500 (fused gat grid)
    const int NBT = 512;           // transform grid (persistent)

    // ---- layer 0 (input dim 9) ----
    transform2_kernel<9><<<NBT, 256, 0, stream>>>(x, Wl0, bl0, Wr0, br0, xlb, xrb);
    gat_fused4_kernel<<<NBN, 256, 0, stream>>>(xlb, xrb, recP, row_ptr,
                                               We0, att0, bo0,
                                               bn_g, bn_b, bn_m, bn_v, hA);

    // ---- layers 1..4 ----
    float* hcur = hA;
    float* hnext = hB;
    for (int i = 0; i < 4; i++) {
        transform2_kernel<64><<<NBT, 256, 0, stream>>>(hcur,
            Wl + (size_t)i * 64 * 64, bl + (size_t)i * 64,
            Wr + (size_t)i * 64 * 64, br + (size_t)i * 64,
            xlb, xrb);
        gat_fused4_kernel<<<NBN, 256, 0, stream>>>(xlb, xrb, recP, row_ptr,
            We + (size_t)i * 3 * 64, att + (size_t)i * 64,
            bo + (size_t)i * 64,
            bn_g + (size_t)(i + 1) * 64, bn_b + (size_t)(i + 1) * 64,
            bn_m + (size_t)(i + 1) * 64, bn_v + (size_t)(i + 1) * 64,
            hnext);
        float* tp = hcur; hcur = hnext; hnext = tp;
    }

    // ---- readout ----
    pool_all_kernel<<<N_GRAPHS, 64, 0, stream>>>(hcur, batch, Wjk, bjk, Whead, bhead,
                                                 (float*)d_out);
}

// Round 8
// 552.980 us; speedup vs baseline: 1.1748x; 1.0452x over previous
//
#include <hip/hip_runtime.h>
#include <math.h>

#define N_NODES 50000
#define N_EDGES 800000
#define N_GRAPHS 512
#define SLOPE 0.2f
static constexpr float EPS_BN = 1e-5f;

typedef float v2f __attribute__((ext_vector_type(2)));

// ---------------- CSR build ----------------

__global__ void hist_kernel(const int* __restrict__ dst, int* __restrict__ cnt) {
    int e = blockIdx.x * blockDim.x + threadIdx.x;
    if (e < N_EDGES) atomicAdd(&cnt[dst[e]], 1);
}

// per-1024-block inclusive scan; row_ptr[n+1] = local inclusive, blk[b] = block total
__global__ void scan1_kernel(const int* __restrict__ cnt, int* __restrict__ row_ptr,
                             int* __restrict__ blk) {
    __shared__ int tmp[1024];
    int t = threadIdx.x;
    int n = blockIdx.x * 1024 + t;
    int v = (n < N_NODES) ? cnt[n] : 0;
    tmp[t] = v;
    __syncthreads();
    for (int off = 1; off < 1024; off <<= 1) {
        int x = (t >= off) ? tmp[t - off] : 0;
        __syncthreads();
        tmp[t] += x;
        __syncthreads();
    }
    if (n < N_NODES) row_ptr[n + 1] = tmp[t];
    if (t == 1023) blk[blockIdx.x] = tmp[t];
}

// finalize row_ptr with cross-block prefix (49 totals, L1-hot) AND write scatter cursors.
__global__ void scan23f_kernel(int* __restrict__ row_ptr, const int* __restrict__ blk,
                               int* __restrict__ fill) {
    int n = blockIdx.x * blockDim.x + threadIdx.x;
    if (n >= N_NODES) return;
    int b = n >> 10;
    int pref = 0;
    for (int i = 0; i < b; ++i) pref += blk[i];
    int v = row_ptr[n + 1] + pref;
    row_ptr[n + 1] = v;
    fill[n + 1] = v;
    if (n == 0) { row_ptr[0] = 0; fill[0] = 0; }
}

// scatter edges into CSR order as ONE 16B record per edge: {src_bits, e0, e1, e2}
__global__ void scatter_kernel(const int* __restrict__ src, const int* __restrict__ dst,
                               const float* __restrict__ ea,
                               int* __restrict__ fill,
                               float4* __restrict__ rec) {
    int e = blockIdx.x * blockDim.x + threadIdx.x;
    if (e < N_EDGES) {
        int pos = atomicAdd(&fill[dst[e]], 1);
        rec[pos] = make_float4(__int_as_float(src[e]),
                               ea[e * 3 + 0], ea[e * 3 + 1], ea[e * 3 + 2]);
    }
}

// ---------------- node transform: per-lane weight columns + SCALAR h-row loads ------
// n is wave-uniform: readfirstlane makes the h-row pointer an SGPR base, so the
// compiler emits s_load_dwordx* for the row; the 2K FMAs read SGPR operands
// (no v_readlane chain, no VALU->SGPR hazards). Worst case: same-address vector
// loads (L1 broadcast), still pipelined.

template <int K>
__global__ __launch_bounds__(256) void transform3_kernel(
    const float* __restrict__ h,
    const float* __restrict__ Wl, const float* __restrict__ bl,
    const float* __restrict__ Wr, const float* __restrict__ br,
    float* __restrict__ xl, float* __restrict__ xr) {
    int t = threadIdx.x;
    int w = t >> 6;
    int k = t & 63;
    float wl[K], wr[K];
#pragma unroll
    for (int j = 0; j < K; j++) { wl[j] = Wl[j * 64 + k]; wr[j] = Wr[j * 64 + k]; }
    float blk = bl[k], brk = br[k];
    int wid = blockIdx.x * 4 + w;
    const int NW = gridDim.x * 4;
    for (int n = wid; n < N_NODES; n += NW) {
        int un = __builtin_amdgcn_readfirstlane(n);
        const float* __restrict__ hrow = h + (size_t)un * K;
        float al = blk, ar = brk;
#pragma unroll
        for (int j = 0; j < K; j++) {
            float hj = hrow[j];
            al = fmaf(hj, wl[j], al);
            ar = fmaf(hj, wr[j], ar);
        }
        xl[(size_t)un * 64 + k] = al;
        xr[(size_t)un * 64 + k] = ar;
    }
}

// ---------------- fused GATv2 layer: packed-f32, one wave/node, 8 edges in flight ----
// lane = 16*q + r: group q covers edge slots, lane holds features 4r..4r+3.
// Feature math on float2 ext-vectors -> v_pk_* (2x f32 per issue).
// leaky(t) = max(t, 0.2t). No max-subtraction softmax (validated R4/R5).
// One 16B record load per edge slot. No LDS, no barriers.

__global__ __launch_bounds__(256) void gat_fused4_kernel(
    const float* __restrict__ xl, const float* __restrict__ xr,
    const float4* __restrict__ recP, const int* __restrict__ row_ptr,
    const float* __restrict__ We, const float* __restrict__ att,
    const float* __restrict__ bo,
    const float* __restrict__ bn_g, const float* __restrict__ bn_b,
    const float* __restrict__ bn_m, const float* __restrict__ bn_v,
    float* __restrict__ hout) {
    int t = threadIdx.x;
    int w = t >> 6;
    int lane = t & 63;
    int q = lane >> 4;       // edge slot within 4-edge group
    int r = lane & 15;       // feature quad
    int k4 = r * 4;
    int n = blockIdx.x * 4 + w;   // grid exact: 12500*4

    float4 we0 = *(const float4*)(We + 0 * 64 + k4);
    float4 we1 = *(const float4*)(We + 64 + k4);
    float4 we2 = *(const float4*)(We + 128 + k4);
    float4 at4 = *(const float4*)(att + k4);
    float4 xq  = *(const float4*)(xr + (size_t)n * 64 + k4);
    v2f we0a = {we0.x, we0.y}, we0b = {we0.z, we0.w};
    v2f we1a = {we1.x, we1.y}, we1b = {we1.z, we1.w};
    v2f we2a = {we2.x, we2.y}, we2b = {we2.z, we2.w};
    v2f ata  = {at4.x, at4.y}, atb  = {at4.z, at4.w};
    v2f xra  = {xq.x, xq.y},   xrb  = {xq.z, xq.w};
    int beg = row_ptr[n], end = row_ptr[n + 1];

    v2f oAa = {0.f, 0.f}, oAb = {0.f, 0.f};
    v2f oBa = {0.f, 0.f}, oBb = {0.f, 0.f};
    float zA = 0.f, zB = 0.f;

    for (int c = beg; c < end; c += 8) {
        int pA = c + q;     bool vA = pA < end; int iA = vA ? pA : beg;
        int pB = c + 4 + q; bool vB = pB < end; int iB = vB ? pB : beg;
        float4 rA = recP[iA];
        float4 rB = recP[iB];
        int sA = __float_as_int(rA.x);
        int sB = __float_as_int(rB.x);
        float4 xA = *(const float4*)(xl + (size_t)sA * 64 + k4);
        float4 xB = *(const float4*)(xl + (size_t)sB * 64 + k4);
        v2f xAa = {xA.x, xA.y}, xAb = {xA.z, xA.w};
        v2f xBa = {xB.x, xB.y}, xBb = {xB.z, xB.w};

        v2f tAa = xAa + xra, tAb = xAb + xrb;
        v2f tBa = xBa + xra, tBb = xBb + xrb;
        tAa = __builtin_elementwise_fma((v2f){rA.y, rA.y}, we0a, tAa);
        tAb = __builtin_elementwise_fma((v2f){rA.y, rA.y}, we0b, tAb);
        tBa = __builtin_elementwise_fma((v2f){rB.y, rB.y}, we0a, tBa);
        tBb = __builtin_elementwise_fma((v2f){rB.y, rB.y}, we0b, tBb);
        tAa = __builtin_elementwise_fma((v2f){rA.z, rA.z}, we1a, tAa);
        tAb = __builtin_elementwise_fma((v2f){rA.z, rA.z}, we1b, tAb);
        tBa = __builtin_elementwise_fma((v2f){rB.z, rB.z}, we1a, tBa);
        tBb = __builtin_elementwise_fma((v2f){rB.z, rB.z}, we1b, tBb);
        tAa = __builtin_elementwise_fma((v2f){rA.w, rA.w}, we2a, tAa);
        tAb = __builtin_elementwise_fma((v2f){rA.w, rA.w}, we2b, tAb);
        tBa = __builtin_elementwise_fma((v2f){rB.w, rB.w}, we2a, tBa);
        tBb = __builtin_elementwise_fma((v2f){rB.w, rB.w}, we2b, tBb);

        // leaky = max(t, 0.2*t)
        tAa = __builtin_elementwise_max(tAa, tAa * SLOPE);
        tAb = __builtin_elementwise_max(tAb, tAb * SLOPE);
        tBa = __builtin_elementwise_max(tBa, tBa * SLOPE);
        tBb = __builtin_elementwise_max(tBb, tBb * SLOPE);

        v2f dA = ata * tAa; dA = __builtin_elementwise_fma(atb, tAb, dA);
        v2f dB = ata * tBa; dB = __builtin_elementwise_fma(atb, tBb, dB);
        float accA = dA.x + dA.y;
        float accB = dB.x + dB.y;

        accA += __shfl_xor(accA, 1, 64);  accB += __shfl_xor(accB, 1, 64);
        accA += __shfl_xor(accA, 2, 64);  accB += __shfl_xor(accB, 2, 64);
        accA += __shfl_xor(accA, 4, 64);  accB += __shfl_xor(accB, 4, 64);
        accA += __shfl_xor(accA, 8, 64);  accB += __shfl_xor(accB, 8, 64);

        float peA = vA ? __expf(accA) : 0.f;
        float peB = vB ? __expf(accB) : 0.f;
        v2f pA2 = {peA, peA}, pB2 = {peB, peB};
        oAa = __builtin_elementwise_fma(pA2, xAa, oAa);
        oAb = __builtin_elementwise_fma(pA2, xAb, oAb);
        oBa = __builtin_elementwise_fma(pB2, xBa, oBa);
        oBb = __builtin_elementwise_fma(pB2, xBb, oBb);
        zA += peA; zB += peB;
    }

    v2f oa = oAa + oBa, ob = oAb + oBb;
    float z = zA + zB;
    float4 o = make_float4(oa.x, oa.y, ob.x, ob.y);
    o.x += __shfl_xor(o.x, 16, 64); o.x += __shfl_xor(o.x, 32, 64);
    o.y += __shfl_xor(o.y, 16, 64); o.y += __shfl_xor(o.y, 32, 64);
    o.z += __shfl_xor(o.z, 16, 64); o.z += __shfl_xor(o.z, 32, 64);
    o.w += __shfl_xor(o.w, 16, 64); o.w += __shfl_xor(o.w, 32, 64);
    z += __shfl_xor(z, 16, 64); z += __shfl_xor(z, 32, 64);

    if (q == 0) {
        float zi = 1.0f / fmaxf(z, 1e-16f);
        float4 bo4 = *(const float4*)(bo + k4);
        float4 g4  = *(const float4*)(bn_g + k4);
        float4 b4  = *(const float4*)(bn_b + k4);
        float4 m4  = *(const float4*)(bn_m + k4);
        float4 v4  = *(const float4*)(bn_v + k4);
        float4 res;
        res.x = fmaxf((o.x * zi + bo4.x - m4.x) * (g4.x / sqrtf(v4.x + EPS_BN)) + b4.x, 0.f);
        res.y = fmaxf((o.y * zi + bo4.y - m4.y) * (g4.y / sqrtf(v4.y + EPS_BN)) + b4.y, 0.f);
        res.z = fmaxf((o.z * zi + bo4.z - m4.z) * (g4.z / sqrtf(v4.z + EPS_BN)) + b4.z, 0.f);
        res.w = fmaxf((o.w * zi + bo4.w - m4.w) * (g4.w / sqrtf(v4.w + EPS_BN)) + b4.w, 0.f);
        *(float4*)(hout + (size_t)n * 64 + k4) = res;
    }
}

// ---------------- readout: all-in-one ----------------

__global__ __launch_bounds__(64) void pool_all_kernel(
    const float* __restrict__ h, const int* __restrict__ batch,
    const float* __restrict__ Wjk, const float* __restrict__ bjk,
    const float* __restrict__ Whead, const float* __restrict__ bhead,
    float* __restrict__ out) {
    int g = blockIdx.x;
    int k = threadIdx.x;
    int lo = 0, hi = N_NODES;
    while (lo < hi) { int mid = (lo + hi) >> 1; if (batch[mid] < g) lo = mid + 1; else hi = mid; }
    int s = lo;
    hi = N_NODES;
    while (lo < hi) { int mid = (lo + hi) >> 1; if (batch[mid] < g + 1) lo = mid + 1; else hi = mid; }
    int e = lo;

    float wc = 0.f;
    for (int j = 0; j < 64; j++) wc = fmaf(Wjk[k * 64 + j], Whead[j], wc);
    float bc = bjk[k] * Whead[k];
    for (int off = 32; off > 0; off >>= 1) bc += __shfl_xor(bc, off, 64);

    float acc = 0.f;
    for (int n = s; n < e; ++n) acc += h[(size_t)n * 64 + k];
    float cnt = (float)(e - s);
    acc /= fmaxf(cnt, 1.0f);
    float v = acc * wc;
    for (int off = 32; off > 0; off >>= 1) v += __shfl_xor(v, off, 64);
    if (k == 0) out[g] = v + bc + bhead[0];
}

// ---------------- launch ----------------

extern "C" void kernel_launch(void* const* d_in, const int* in_sizes, int n_in,
                              void* d_out, int out_size, void* d_ws, size_t ws_size,
                              hipStream_t stream) {
    const float* x     = (const float*)d_in[0];
    const float* ea    = (const float*)d_in[1];
    const float* Wl0   = (const float*)d_in[2];
    const float* Wr0   = (const float*)d_in[3];
    const float* bl0   = (const float*)d_in[4];
    const float* br0   = (const float*)d_in[5];
    const float* We0   = (const float*)d_in[6];
    const float* att0  = (const float*)d_in[7];
    const float* bo0   = (const float*)d_in[8];
    const float* Wl    = (const float*)d_in[9];
    const float* Wr    = (const float*)d_in[10];
    const float* bl    = (const float*)d_in[11];
    const float* br    = (const float*)d_in[12];
    const float* We    = (const float*)d_in[13];
    const float* att   = (const float*)d_in[14];
    const float* bo    = (const float*)d_in[15];
    const float* bn_g  = (const float*)d_in[16];
    const float* bn_b  = (const float*)d_in[17];
    const float* bn_m  = (const float*)d_in[18];
    const float* bn_v  = (const float*)d_in[19];
    const float* Wjk   = (const float*)d_in[20];
    const float* bjk   = (const float*)d_in[21];
    const float* Whead = (const float*)d_in[22];
    const float* bhead = (const float*)d_in[23];
    const int* edge_index = (const int*)d_in[24];
    const int* batch      = (const int*)d_in[25];

    const int* srcIdx = edge_index;            // edge_index[0]
    const int* dstIdx = edge_index + N_EDGES;  // edge_index[1]

    char* ws = (char*)d_ws;
    size_t off = 0;
    auto alloc = [&](size_t bytes) -> void* {
        void* p = ws + off;
        off += (bytes + 255) & ~(size_t)255;
        return p;
    };
    float* hA      = (float*)alloc((size_t)N_NODES * 64 * 4);
    float* hB      = (float*)alloc((size_t)N_NODES * 64 * 4);
    float* xlb     = (float*)alloc((size_t)N_NODES * 64 * 4);
    float* xrb     = (float*)alloc((size_t)N_NODES * 64 * 4);
    int*   row_ptr = (int*)alloc((size_t)(N_NODES + 1) * 4);
    int*   fill    = (int*)alloc((size_t)(N_NODES + 1) * 4);
    int*   blk     = (int*)alloc(64 * 4);
    float4* recP   = (float4*)alloc((size_t)N_EDGES * 16);

    // ---- CSR build (sort edges by dst) ----
    hipMemsetAsync(fill, 0, (size_t)N_NODES * 4, stream);
    hist_kernel<<<(N_EDGES + 255) / 256, 256, 0, stream>>>(dstIdx, fill);
    const int SCB = (N_NODES + 1023) / 1024;  // 49
    scan1_kernel<<<SCB, 1024, 0, stream>>>(fill, row_ptr, blk);
    scan23f_kernel<<<(N_NODES + 255) / 256, 256, 0, stream>>>(row_ptr, blk, fill);
    scatter_kernel<<<(N_EDGES + 255) / 256, 256, 0, stream>>>(srcIdx, dstIdx, ea, fill, recP);

    const int NBN = N_NODES / 4;   // 12500 (fused gat grid)
    const int NBT = 768;           // transform grid (persistent, ~3 blocks/CU)

    // ---- layer 0 (input dim 9) ----
    transform3_kernel<9><<<NBT, 256, 0, stream>>>(x, Wl0, bl0, Wr0, br0, xlb, xrb);
    gat_fused4_kernel<<<NBN, 256, 0, stream>>>(xlb, xrb, recP, row_ptr,
                                               We0, att0, bo0,
                                               bn_g, bn_b, bn_m, bn_v, hA);

    // ---- layers 1..4 ----
    float* hcur = hA;
    float* hnext = hB;
    for (int i = 0; i < 4; i++) {
        transform3_kernel<64><<<NBT, 256, 0, stream>>>(hcur,
            Wl + (size_t)i * 64 * 64, bl + (size_t)i * 64,
            Wr + (size_t)i * 64 * 64, br + (size_t)i * 64,
            xlb, xrb);
        gat_fused4_kernel<<<NBN, 256, 0, stream>>>(xlb, xrb, recP, row_ptr,
            We + (size_t)i * 3 * 64, att + (size_t)i * 64,
            bo + (size_t)i * 64,
            bn_g + (size_t)(i + 1) * 64, bn_b + (size_t)(i + 1) * 64,
            bn_m + (size_t)(i + 1) * 64, bn_v + (size_t)(i + 1) * 64,
            hnext);
        float* tp = hcur; hcur = hnext; hnext = tp;
    }

    // ---- readout ----
    pool_all_kernel<<<N_GRAPHS, 64, 0, stream>>>(hcur, batch, Wjk, bjk, Whead, bhead,
                                                 (float*)d_out);
}